// Round 5
// baseline (228.644 us; speedup 1.0000x reference)
//
#include <hip/hip_runtime.h>

// IWT (inverse 2x2 Haar): x (32, 256, 64, 64) f32 -> out (32, 64, 128, 128) f32
// Input channel dim = 64 groups * 4 subbands {cA, cH, cV, cD}.
// out[2h  ][2w  ] = (a + h + v + d) * 0.5
// out[2h  ][2w+1] = (a + h - v - d) * 0.5
// out[2h+1][2w  ] = (a - h + v - d) * 0.5
// out[2h+1][2w+1] = (a - h - v + d) * 0.5
//
// v4: back to the v1 champion structure (one-shot grid, float2 loads that
// are 512B-dense per wave instruction, float4 stores that are fully dense),
// NO nontemporal stores (v3b showed NT cost ~9%: bypassing L2/L3 forfeits
// write-combining/deferred writeback, and the input gets evicted by the
// inter-iteration poison fills regardless).
// One new lever: 2-tile ILP batching. Each thread processes tile tid and
// tile tid + 2^21 (bc offset +1024) -> 8 independent dwordx2 loads in
// flight per thread instead of 4, 8192 blocks instead of 16384. Address
// math for the second tile is a constant offset (base+2^23, ob+2^22), so
// no extra VALU beyond the adds. Wave-level density of every vmem
// instruction is unchanged.

#define NTHREAD 256
#define NBLOCK  8192   // 2^21 threads, 2 tiles each = 2^22 tiles total

typedef float f32x2 __attribute__((ext_vector_type(2)));
typedef float f32x4 __attribute__((ext_vector_type(4)));

__global__ __launch_bounds__(NTHREAD) void iwt_kernel(const f32x2* __restrict__ xv,
                                                      f32x4* __restrict__ ov) {
    int tid = blockIdx.x * NTHREAD + threadIdx.x;

    // tile t: w2 = t & 31, h = (t>>5) & 63, bc = t >> 11
    // input f32x2 idx for subband s: (4*bc + s)*2048 + h*32 + w2
    // output f32x4 idx row 2h: bc*4096 + h*64 + w2 ; row 2h+1: +32
    int base0 = ((tid >> 11) << 13) + (((tid >> 5) & 63) << 5) + (tid & 31);
    int base1 = base0 + (1 << 23);   // tile tid + 2^21  (bc + 1024)
    int ob0   = ((tid >> 11) << 12) + (((tid >> 5) & 63) << 6) + (tid & 31);
    int ob1   = ob0 + (1 << 22);

    // 8 independent loads in flight
    f32x2 aA = xv[base0];
    f32x2 hA = xv[base0 + 2048];
    f32x2 vA = xv[base0 + 4096];
    f32x2 dA = xv[base0 + 6144];
    f32x2 aB = xv[base1];
    f32x2 hB = xv[base1 + 2048];
    f32x2 vB = xv[base1 + 4096];
    f32x2 dB = xv[base1 + 6144];

    {   // tile A
        float px = aA.x + dA.x, qx = aA.x - dA.x, rx = hA.x + vA.x, sx = hA.x - vA.x;
        float py = aA.y + dA.y, qy = aA.y - dA.y, ry = hA.y + vA.y, sy = hA.y - vA.y;
        f32x4 r0, r1;
        r0.x = (px + rx) * 0.5f;  r0.y = (qx + sx) * 0.5f;   // row 2h:   o00 o01
        r0.z = (py + ry) * 0.5f;  r0.w = (qy + sy) * 0.5f;
        r1.x = (qx - sx) * 0.5f;  r1.y = (px - rx) * 0.5f;   // row 2h+1: o10 o11
        r1.z = (qy - sy) * 0.5f;  r1.w = (py - ry) * 0.5f;
        ov[ob0]      = r0;
        ov[ob0 + 32] = r1;
    }
    {   // tile B
        float px = aB.x + dB.x, qx = aB.x - dB.x, rx = hB.x + vB.x, sx = hB.x - vB.x;
        float py = aB.y + dB.y, qy = aB.y - dB.y, ry = hB.y + vB.y, sy = hB.y - vB.y;
        f32x4 r0, r1;
        r0.x = (px + rx) * 0.5f;  r0.y = (qx + sx) * 0.5f;
        r0.z = (py + ry) * 0.5f;  r0.w = (qy + sy) * 0.5f;
        r1.x = (qx - sx) * 0.5f;  r1.y = (px - rx) * 0.5f;
        r1.z = (qy - sy) * 0.5f;  r1.w = (py - ry) * 0.5f;
        ov[ob1]      = r0;
        ov[ob1 + 32] = r1;
    }
}

extern "C" void kernel_launch(void* const* d_in, const int* in_sizes, int n_in,
                              void* d_out, int out_size, void* d_ws, size_t ws_size,
                              hipStream_t stream) {
    const f32x2* x = (const f32x2*)d_in[0];
    f32x4* out = (f32x4*)d_out;

    iwt_kernel<<<NBLOCK, NTHREAD, 0, stream>>>(x, out);
}

// Round 6
// 223.487 us; speedup vs baseline: 1.0231x; 1.0231x over previous
//
#include <hip/hip_runtime.h>

// IWT (inverse 2x2 Haar): x (32, 256, 64, 64) f32 -> out (32, 64, 128, 128) f32
// Input channel dim = 64 groups * 4 subbands {cA, cH, cV, cD}.
// out[2h  ][2w  ] = (a + h + v + d) * 0.5
// out[2h  ][2w+1] = (a + h - v - d) * 0.5
// out[2h+1][2w  ] = (a - h + v - d) * 0.5
// out[2h+1][2w+1] = (a - h - v + d) * 0.5
//
// v5: v1 champion structure, ONE change: 1024-thread blocks (4096 blocks)
// instead of 256-thread blocks (16384 blocks).
//   Evidence so far: v1 (1 tile/thread, float2 loads = 512B-dense/instr,
//   float4 stores = dense) ~60us kernel beats every footprint-widening
//   variant (v2 float4 loads+stride-2 stores, v3b persistent+NT, v4 2-tile
//   ILP) which all land ~67us. Per-wave MLP, load width, and NT policy are
//   ruled out as levers. The one unexplained counter: Occupancy 63% on a
//   20-VGPR no-LDS kernel => WG launch/drain churn (16384 WGs x ~2us life).
//   Fusing 4 WGs into 1 leaves every wave's addresses and instruction
//   stream identical and only cuts launch count 4x.

#define NTHREAD 1024
#define NBLOCK  4096    // 4,194,304 threads, 1 tile each

typedef float f32x2 __attribute__((ext_vector_type(2)));
typedef float f32x4 __attribute__((ext_vector_type(4)));

__global__ __launch_bounds__(NTHREAD) void iwt_kernel(const f32x2* __restrict__ xv,
                                                      f32x4* __restrict__ ov) {
    int tid = blockIdx.x * NTHREAD + threadIdx.x;

    // tile t: w2 = t & 31, h = (t>>5) & 63, bc = t >> 11
    // input f32x2 idx for subband s: (4*bc + s)*2048 + h*32 + w2
    int base = ((tid >> 11) << 13) + (((tid >> 5) & 63) << 5) + (tid & 31);
    f32x2 a  = xv[base];
    f32x2 hh = xv[base + 2048];
    f32x2 v  = xv[base + 4096];
    f32x2 d  = xv[base + 6144];

    // butterfly: p=a+d, q=a-d, r=h+v, s=h-v
    float px = a.x + d.x, qx = a.x - d.x, rx = hh.x + v.x, sx = hh.x - v.x;
    float py = a.y + d.y, qy = a.y - d.y, ry = hh.y + v.y, sy = hh.y - v.y;

    f32x4 r0, r1;
    r0.x = (px + rx) * 0.5f;  r0.y = (qx + sx) * 0.5f;   // row 2h:   o00 o01
    r0.z = (py + ry) * 0.5f;  r0.w = (qy + sy) * 0.5f;
    r1.x = (qx - sx) * 0.5f;  r1.y = (px - rx) * 0.5f;   // row 2h+1: o10 o11
    r1.z = (qy - sy) * 0.5f;  r1.w = (py - ry) * 0.5f;

    // out f32x4 idx: row 2h at bc*4096 + h*64 + w2 ; row 2h+1 at +32
    int ob = ((tid >> 11) << 12) + (((tid >> 5) & 63) << 6) + (tid & 31);
    ov[ob]      = r0;
    ov[ob + 32] = r1;
}

extern "C" void kernel_launch(void* const* d_in, const int* in_sizes, int n_in,
                              void* d_out, int out_size, void* d_ws, size_t ws_size,
                              hipStream_t stream) {
    const f32x2* x = (const f32x2*)d_in[0];
    f32x4* out = (f32x4*)d_out;

    iwt_kernel<<<NBLOCK, NTHREAD, 0, stream>>>(x, out);
}